// Round 7
// baseline (512.775 us; speedup 1.0000x reference)
//
#include <hip/hip_runtime.h>
#include <stdint.h>

#define N 8192
#define D 256
#define L 4
#define K 1024
#define E 8

#define TM 128            // samples per dist block
#define TN 128            // codes per dist block
#define BK 32             // k-chunk (one MFMA k-step)
#define KSPLIT (K / TN)   // 8
#define MAXTILES (N / TM + E)   // 72
#define MARGIN 4e-4f

typedef unsigned long long u64;
typedef __attribute__((ext_vector_type(8))) short bf16x8;
typedef __attribute__((ext_vector_type(4))) float f32x4;

__device__ __forceinline__ unsigned f2sort(float f) {
    unsigned u = __float_as_uint(f);
    return (u & 0x80000000u) ? ~u : (u | 0x80000000u);
}
__device__ __forceinline__ float sort2f(unsigned s) {
    unsigned u = (s & 0x80000000u) ? (s & 0x7fffffffu) : ~s;
    return __uint_as_float(u);
}
__device__ __forceinline__ u64 umin64(u64 a, u64 b) { return a < b ? a : b; }
__device__ __forceinline__ u64 umax64(u64 a, u64 b) { return a > b ? a : b; }

// manual RNE f32->bf16 (finite inputs)
__device__ __forceinline__ unsigned short f2bf(float f) {
    unsigned u = __float_as_uint(f);
    unsigned r = (u + 0x7fffu + ((u >> 16) & 1u)) >> 16;
    return (unsigned short)r;
}
__device__ __forceinline__ float bf2f(unsigned short h) {
    return __uint_as_float(((unsigned)h) << 16);
}

__device__ __forceinline__ void gload_lds16(const void* g, void* l) {
    __builtin_amdgcn_global_load_lds(
        (const __attribute__((address_space(1))) unsigned int*)(g),
        (__attribute__((address_space(3))) unsigned int*)(l), 16, 0, 0);
}

// ------------------------------------------------------------- gate ---------
// NOTE: no atomics here — 8192 same-line atomicAdds cost ~98us (R4 counters).
__global__ void gate_kernel(const float* __restrict__ x,
                            const float* __restrict__ gW,
                            const float* __restrict__ gb,
                            int* __restrict__ eid,
                            float* __restrict__ out_idx,
                            unsigned short* __restrict__ rhi,
                            unsigned short* __restrict__ rlo) {
    int wid = threadIdx.x >> 6, lane = threadIdx.x & 63;
    int n = blockIdx.x * 4 + wid;
    float4 xv = *reinterpret_cast<const float4*>(x + (size_t)n * D + lane * 4);

    ushort4 h4, l4;
    h4.x = f2bf(xv.x); l4.x = f2bf(xv.x - bf2f(h4.x));
    h4.y = f2bf(xv.y); l4.y = f2bf(xv.y - bf2f(h4.y));
    h4.z = f2bf(xv.z); l4.z = f2bf(xv.z - bf2f(h4.z));
    h4.w = f2bf(xv.w); l4.w = f2bf(xv.w - bf2f(h4.w));
    *reinterpret_cast<ushort4*>(rhi + (size_t)n * D + lane * 4) = h4;
    *reinterpret_cast<ushort4*>(rlo + (size_t)n * D + lane * 4) = l4;

    float xa[4] = {xv.x, xv.y, xv.z, xv.w};
    float a[8];
#pragma unroll
    for (int e = 0; e < 8; e++) a[e] = 0.f;
    const float* wr = gW + (size_t)(lane * 4) * E;
#pragma unroll
    for (int i = 0; i < 4; i++) {
        float xs = xa[i];
        float4 w0 = *reinterpret_cast<const float4*>(wr + i * E);
        float4 w1 = *reinterpret_cast<const float4*>(wr + i * E + 4);
        a[0] = fmaf(xs, w0.x, a[0]); a[1] = fmaf(xs, w0.y, a[1]);
        a[2] = fmaf(xs, w0.z, a[2]); a[3] = fmaf(xs, w0.w, a[3]);
        a[4] = fmaf(xs, w1.x, a[4]); a[5] = fmaf(xs, w1.y, a[5]);
        a[6] = fmaf(xs, w1.z, a[6]); a[7] = fmaf(xs, w1.w, a[7]);
    }
#pragma unroll
    for (int off = 32; off > 0; off >>= 1) {
#pragma unroll
        for (int e = 0; e < 8; e++) a[e] += __shfl_xor(a[e], off);
    }
    if (lane == 0) {
        int be = 0;
        float bv = a[0] + gb[0];
        for (int e = 1; e < 8; e++) {
            float v = a[e] + gb[e];
            if (v > bv) { bv = v; be = e; }
        }
        eid[n] = be;
        out_idx[(size_t)n * (L + 1) + L] = (float)be;
    }
}

// ---------------- deterministic counting sort by expert (zero atomics) ------
__global__ __launch_bounds__(256)
void bucket_kernel(const int* __restrict__ eid, int* __restrict__ counts,
                   int* __restrict__ order) {
    __shared__ u64 wtot_lo[4], wtot_hi[4];
    __shared__ int base[E];
    int tid = threadIdx.x, lane = tid & 63, wv = tid >> 6;
    int n0 = tid * 32;
    int eids[32];
    u64 lo = 0, hi = 0;
#pragma unroll
    for (int j = 0; j < 32; j++) {
        int e = eid[n0 + j];
        eids[j] = e;
        if (e < 4) lo += 1ull << (e * 16);
        else       hi += 1ull << ((e - 4) * 16);
    }
    u64 slo = lo, shi = hi;
#pragma unroll
    for (int d = 1; d < 64; d <<= 1) {
        u64 t1 = __shfl_up(slo, d);
        u64 t2 = __shfl_up(shi, d);
        if (lane >= d) { slo += t1; shi += t2; }
    }
    if (lane == 63) { wtot_lo[wv] = slo; wtot_hi[wv] = shi; }
    __syncthreads();
    u64 wofflo = 0, woffhi = 0;
    for (int w = 0; w < wv; w++) { wofflo += wtot_lo[w]; woffhi += wtot_hi[w]; }
    u64 exlo = wofflo + slo - lo;
    u64 exhi = woffhi + shi - hi;
    if (tid == 0) {
        u64 tlo = wtot_lo[0] + wtot_lo[1] + wtot_lo[2] + wtot_lo[3];
        u64 thi = wtot_hi[0] + wtot_hi[1] + wtot_hi[2] + wtot_hi[3];
        int a = 0;
#pragma unroll
        for (int e = 0; e < 4; e++) {
            int c = (int)((tlo >> (e * 16)) & 0xffff);
            counts[e] = c; base[e] = a; a += c;
        }
#pragma unroll
        for (int e = 0; e < 4; e++) {
            int c = (int)((thi >> (e * 16)) & 0xffff);
            counts[4 + e] = c; base[4 + e] = a; a += c;
        }
    }
    __syncthreads();
#pragma unroll
    for (int j = 0; j < 32; j++) {
        int e = eids[j];
        int p;
        if (e < 4) { p = (int)((exlo >> (e * 16)) & 0xffff); exlo += 1ull << (e * 16); }
        else       { p = (int)((exhi >> ((e - 4) * 16)) & 0xffff); exhi += 1ull << ((e - 4) * 16); }
        order[base[e] + p] = n0 + j;
    }
}

// --------------------------------------- codebook prep: c2 + bf16 hi/lo -----
__global__ void cb_prep(const float* __restrict__ cbs, float* __restrict__ c2,
                        unsigned short* __restrict__ cbhi,
                        unsigned short* __restrict__ cblo) {
    int wid = threadIdx.x >> 6, lane = threadIdx.x & 63;
    size_t row = (size_t)blockIdx.x * 4 + wid;
    float4 v = *reinterpret_cast<const float4*>(cbs + row * D + lane * 4);
    ushort4 h4, l4;
    h4.x = f2bf(v.x); l4.x = f2bf(v.x - bf2f(h4.x));
    h4.y = f2bf(v.y); l4.y = f2bf(v.y - bf2f(h4.y));
    h4.z = f2bf(v.z); l4.z = f2bf(v.z - bf2f(h4.z));
    h4.w = f2bf(v.w); l4.w = f2bf(v.w - bf2f(h4.w));
    *reinterpret_cast<ushort4*>(cbhi + row * D + lane * 4) = h4;
    *reinterpret_cast<ushort4*>(cblo + row * D + lane * 4) = l4;
    float s = v.x * v.x + v.y * v.y + v.z * v.z + v.w * v.w;
#pragma unroll
    for (int off = 32; off > 0; off >>= 1) s += __shfl_xor(s, off);
    if (lane == 0) c2[row] = s;
}

// ------------------------------------------------------------ distances -----
__global__ __launch_bounds__(256, 2)
void dist_kernel(const unsigned short* __restrict__ rhi,
                 const unsigned short* __restrict__ rlo,
                 const unsigned short* __restrict__ cbhi,
                 const unsigned short* __restrict__ cblo,
                 const float* __restrict__ c2l,
                 const int* __restrict__ order, const int* __restrict__ counts,
                 uint4* __restrict__ ws2) {
    __shared__ short lA[2][TM * 64];
    __shared__ short lB[2][TN * 64];

    int bx = blockIdx.x;
    int tile = bx >> 3, kc = bx & 7;

    int eoffL[E + 1]; int a = 0;
#pragma unroll
    for (int i = 0; i < E; i++) { eoffL[i] = a; a += counts[i]; }
    eoffL[E] = a;

    int e = -1, lt = 0, cnt = 0, cum = 0;
    for (int i = 0; i < E; i++) {
        int c = counts[i];
        int t = (c + TM - 1) / TM;
        if (tile < cum + t) { e = i; lt = tile - cum; cnt = c; break; }
        cum += t;
    }
    if (e < 0) return;
    int base = eoffL[e] + lt * TM;
    int mcnt = min(TM, cnt - lt * TM);
    int k0 = kc * TN;

    int tid = threadIdx.x;
    int lane = tid & 63, wv = tid >> 6;
    int wr = wv >> 1, wc = wv & 1;

    int srow[4], scol[4], nid[4];
#pragma unroll
    for (int i = 0; i < 4; i++) {
        int s = i * 256 + tid;
        srow[i] = s >> 3;
        scol[i] = (s & 7) ^ (srow[i] & 7);
        nid[i] = 0;
    }
#pragma unroll
    for (int i = 0; i < 4; i++) nid[i] = order[min(base + srow[i], N - 1)];

    const size_t cbbase = ((size_t)e * K + k0) * D;

    f32x4 acc[4][4];
#pragma unroll
    for (int fr = 0; fr < 4; fr++)
#pragma unroll
        for (int fc = 0; fc < 4; fc++)
            acc[fr][fc] = (f32x4){0.f, 0.f, 0.f, 0.f};

    auto STAGE = [&](int buf, int ck) {
        int dc = ck * BK;
#pragma unroll
        for (int i = 0; i < 4; i++) {
            int s = i * 256 + tid, c = scol[i];
            const unsigned short* src = (c < 4)
                ? (rhi + (size_t)nid[i] * D + dc + c * 8)
                : (rlo + (size_t)nid[i] * D + dc + (c - 4) * 8);
            gload_lds16(src, &lA[buf][s * 8]);
        }
#pragma unroll
        for (int i = 0; i < 4; i++) {
            int s = i * 256 + tid, c = scol[i];
            const unsigned short* src = (c < 4)
                ? (cbhi + cbbase + (size_t)srow[i] * D + dc + c * 8)
                : (cblo + cbbase + (size_t)srow[i] * D + dc + (c - 4) * 8);
            gload_lds16(src, &lB[buf][s * 8]);
        }
    };

    int q = lane >> 4, rL = lane & 15;
    STAGE(0, 0);
    for (int ck = 0; ck < D / BK; ck++) {
        __syncthreads();
        if (ck < D / BK - 1) STAGE((ck + 1) & 1, ck + 1);
        int buf = ck & 1;
        bf16x8 ah[4], al[4];
#pragma unroll
        for (int fr = 0; fr < 4; fr++) {
            int row = wr * 64 + fr * 16 + rL;
            ah[fr] = *reinterpret_cast<const bf16x8*>(&lA[buf][row * 64 + ((q) ^ (row & 7)) * 8]);
            al[fr] = *reinterpret_cast<const bf16x8*>(&lA[buf][row * 64 + ((4 + q) ^ (row & 7)) * 8]);
        }
#pragma unroll
        for (int fc = 0; fc < 4; fc++) {
            int row = wc * 64 + fc * 16 + rL;
            bf16x8 bh = *reinterpret_cast<const bf16x8*>(&lB[buf][row * 64 + ((q) ^ (row & 7)) * 8]);
            bf16x8 bl = *reinterpret_cast<const bf16x8*>(&lB[buf][row * 64 + ((4 + q) ^ (row & 7)) * 8]);
#pragma unroll
            for (int fr = 0; fr < 4; fr++) {
                acc[fr][fc] = __builtin_amdgcn_mfma_f32_16x16x32_bf16(ah[fr], bh, acc[fr][fc], 0, 0, 0);
                acc[fr][fc] = __builtin_amdgcn_mfma_f32_16x16x32_bf16(ah[fr], bl, acc[fr][fc], 0, 0, 0);
                acc[fr][fc] = __builtin_amdgcn_mfma_f32_16x16x32_bf16(al[fr], bh, acc[fr][fc], 0, 0, 0);
            }
        }
    }

    int cL = lane & 15;
#pragma unroll
    for (int fr = 0; fr < 4; fr++) {
#pragma unroll
        for (int j = 0; j < 4; j++) {
            int row_local = wr * 64 + fr * 16 + q * 4 + j;
            u64 best = ~0ull; unsigned sec = 0xFFFFFFFFu;
#pragma unroll
            for (int fc = 0; fc < 4; fc++) {
                int col = k0 + wc * 64 + fc * 16 + cL;
                float dist = c2l[e * K + col] - 2.0f * acc[fr][fc][j];
                u64 kk = ((u64)f2sort(dist) << 32) | (unsigned)col;
                u64 mx = umax64(best, kk);
                best = umin64(best, kk);
                sec = min(sec, (unsigned)(mx >> 32));
            }
#pragma unroll
            for (int m = 1; m < 16; m <<= 1) {
                u64 ob = __shfl_xor(best, m, 16);
                unsigned os = __shfl_xor(sec, m, 16);
                u64 mx = umax64(best, ob);
                best = umin64(best, ob);
                sec = min(min(sec, os), (unsigned)(mx >> 32));
            }
            if (cL == 0 && row_local < mcnt) {
                int n = order[base + row_local];
                uint4 v;
                v.x = (unsigned)(best & 0xffffffffu);
                v.y = (unsigned)(best >> 32);
                v.z = sec; v.w = 0;
                ws2[(size_t)n * 16 + kc * 2 + wc] = v;
            }
        }
    }
}

// ---------------- resolve + block-cooperative exact rescore + update --------
// 2048 blocks x 4 samples (R5: 256 blocks was latency-bound, Occupancy 1.5%).
__global__ __launch_bounds__(256)
void finalize_kernel(const float* __restrict__ rin, float* __restrict__ resid,
                     const float* __restrict__ cbl, const uint4* __restrict__ ws2,
                     const int* __restrict__ eid, const float* __restrict__ x,
                     float* __restrict__ out, float* __restrict__ lossb,
                     const float* __restrict__ c2l,
                     unsigned short* __restrict__ rhi,
                     unsigned short* __restrict__ rlo, int l) {
    __shared__ int s_idx[4];
    __shared__ int s_eid[4];
    __shared__ int s_flag[4];
    __shared__ int s_fcount;
    __shared__ u64 s_rb[4];
    __shared__ float s_ls[4];

    int tid = threadIdx.x, lane = tid & 63, wv = tid >> 6;
    int n0 = blockIdx.x * 4;
    if (tid == 0) s_fcount = 0;
    __syncthreads();

    // ---- phase A: wave 0 resolves all 4 samples (16 lanes each)
    if (wv == 0) {
        int sloc = lane >> 4;
        int n = n0 + sloc;
        int l16 = lane & 15;
        uint4 ev = ws2[(size_t)n * 16 + l16];
        u64 best = ((u64)ev.y << 32) | ev.x;
        unsigned sec = ev.z;
#pragma unroll
        for (int m = 1; m < 16; m <<= 1) {
            u64 ob = __shfl_xor(best, m, 16);
            unsigned os = __shfl_xor(sec, m, 16);
            u64 mx = umax64(best, ob);
            best = umin64(best, ob);
            sec = min(min(sec, os), (unsigned)(mx >> 32));
        }
        if (l16 == 0) {
            s_idx[sloc] = (int)(best & 0xffffffffu);
            s_eid[sloc] = eid[n];
            float bd = sort2f((unsigned)(best >> 32));
            float sd = sort2f(sec);
            if (sd - bd < MARGIN) {
                int p = atomicAdd(&s_fcount, 1);
                s_flag[p] = sloc;
            }
        }
    }
    __syncthreads();
    int fc = s_fcount;

    // ---- phase B: exact fp32 rescore of flagged samples (rare)
    for (int f = 0; f < fc; f++) {
        int sloc = s_flag[f];
        int n = n0 + sloc, e = s_eid[sloc];
        const float* rrow = rin + (size_t)n * D;
        u64 rb = ~0ull;
        for (int c = 0; c < 4; c++) {
            int k = c * 256 + tid;
            const float* crow = cbl + ((size_t)e * K + k) * D;
            float dot = 0.f;
#pragma unroll
            for (int d0 = 0; d0 < D; d0 += 4) {
                float4 c4 = *reinterpret_cast<const float4*>(crow + d0);
                float4 s4 = *reinterpret_cast<const float4*>(rrow + d0);
                dot = fmaf(s4.x, c4.x, dot);
                dot = fmaf(s4.y, c4.y, dot);
                dot = fmaf(s4.z, c4.z, dot);
                dot = fmaf(s4.w, c4.w, dot);
            }
            float dist = c2l[e * K + k] - 2.0f * dot;
            rb = umin64(rb, ((u64)f2sort(dist) << 32) | (unsigned)k);
        }
#pragma unroll
        for (int m = 1; m < 64; m <<= 1) rb = umin64(rb, __shfl_xor(rb, m));
        if (lane == 0) s_rb[wv] = rb;
        __syncthreads();
        if (tid == 0) {
            rb = umin64(umin64(s_rb[0], s_rb[1]), umin64(s_rb[2], s_rb[3]));
            s_idx[sloc] = (int)(rb & 0xffffffffu);
        }
        __syncthreads();
    }

    // ---- phase C: streaming update; wave wv owns sample wv (64 f4-chunks)
    int sloc = wv, f4p = lane;
    int n = n0 + sloc;
    int e = s_eid[sloc], idx = s_idx[sloc];
    const float* qrow = cbl + ((size_t)e * K + idx) * D;
    float4 q4 = *reinterpret_cast<const float4*>(qrow + f4p * 4);
    float4 r4 = *reinterpret_cast<const float4*>(rin + (size_t)n * D + f4p * 4);
    float dx = q4.x - r4.x, dy = q4.y - r4.y, dz = q4.z - r4.z, dw = q4.w - r4.w;
    float lsum = dx * dx + dy * dy + dz * dz + dw * dw;
    float4 nr = make_float4(r4.x - q4.x, r4.y - q4.y, r4.z - q4.z, r4.w - q4.w);
    if (l < L - 1) {
        *reinterpret_cast<float4*>(resid + (size_t)n * D + f4p * 4) = nr;
        ushort4 h4, l4w;
        h4.x = f2bf(nr.x); l4w.x = f2bf(nr.x - bf2f(h4.x));
        h4.y = f2bf(nr.y); l4w.y = f2bf(nr.y - bf2f(h4.y));
        h4.z = f2bf(nr.z); l4w.z = f2bf(nr.z - bf2f(h4.z));
        h4.w = f2bf(nr.w); l4w.w = f2bf(nr.w - bf2f(h4.w));
        *reinterpret_cast<ushort4*>(rhi + (size_t)n * D + f4p * 4) = h4;
        *reinterpret_cast<ushort4*>(rlo + (size_t)n * D + f4p * 4) = l4w;
    } else {
        float4 x4 = *reinterpret_cast<const float4*>(x + (size_t)n * D + f4p * 4);
        float4 xq = make_float4(x4.x - nr.x, x4.y - nr.y, x4.z - nr.z, x4.w - nr.w);
        *reinterpret_cast<float4*>(out + (size_t)n * D + f4p * 4) = xq;
    }
    if (f4p == 0)
        out[(size_t)N * D + 1 + (size_t)n * (L + 1) + l] = (float)idx;
#pragma unroll
    for (int m = 1; m < 64; m <<= 1) lsum += __shfl_xor(lsum, m);
    if (lane == 0) s_ls[wv] = lsum;
    __syncthreads();
    if (tid == 0)
        atomicAdd(&lossb[blockIdx.x & 31], s_ls[0] + s_ls[1] + s_ls[2] + s_ls[3]);
}

__global__ void loss_fin_kernel(const float* __restrict__ lossb, float* __restrict__ out) {
    float s = 0.f;
    for (int i = 0; i < 32; i++) s += lossb[i];
    out[(size_t)N * D] = 2.0f * s / ((float)N * (float)D * (float)L);
}

// ----------------------------------------------------------------------------
extern "C" void kernel_launch(void* const* d_in, const int* in_sizes, int n_in,
                              void* d_out, int out_size, void* d_ws, size_t ws_size,
                              hipStream_t stream) {
    const float* x   = (const float*)d_in[0];
    // d_in[1] = labels (unused)
    const float* cbs = (const float*)d_in[2];
    const float* gW  = (const float*)d_in[3];
    const float* gb  = (const float*)d_in[4];
    float* out = (float*)d_out;

    char* ws = (char*)d_ws;
    float*          resid = (float*)(ws);                       //  8,388,608
    unsigned short* rhi   = (unsigned short*)(ws + 8388608);    //  4,194,304
    unsigned short* rlo   = (unsigned short*)(ws + 12582912);   //  4,194,304
    unsigned short* cbhi  = (unsigned short*)(ws + 16777216);   // 16,777,216
    unsigned short* cblo  = (unsigned short*)(ws + 33554432);   // 16,777,216
    float*          c2    = (float*)(ws + 50331648);            //    131,072
    int*            eid   = (int*)(ws + 50462720);              //     32,768
    int*            order = (int*)(ws + 50495488);              //     33,280
    uint4*          ws2   = (uint4*)(ws + 50528768);            //  2,097,152
    char*           smallp = ws + 52625920;
    int*   counts  = (int*)(smallp);          // 32 B
    float* lossb   = (float*)(smallp + 128);  // 128 B (32 buckets)

    hipMemsetAsync(smallp, 0, 256, stream);

    gate_kernel<<<N / 4, 256, 0, stream>>>(x, gW, gb, eid,
                                           out + (size_t)N * D + 1, rhi, rlo);
    bucket_kernel<<<1, 256, 0, stream>>>(eid, counts, order);
    cb_prep<<<(L * E * K) / 4, 256, 0, stream>>>(cbs, c2, cbhi, cblo);

    for (int l = 0; l < L; l++) {
        const float* rin = (l == 0) ? x : resid;
        size_t cboff = (size_t)l * E * K * D;
        const float* c2l = c2 + (size_t)l * E * K;
        dist_kernel<<<MAXTILES * KSPLIT, 256, 0, stream>>>(
            rhi, rlo, cbhi + cboff, cblo + cboff, c2l, order, counts, ws2);
        finalize_kernel<<<N / 4, 256, 0, stream>>>(
            rin, resid, cbs + cboff, ws2, eid, x, out, lossb, c2l, rhi, rlo, l);
    }
    loss_fin_kernel<<<1, 1, 0, stream>>>(lossb, out);
}

// Round 9
// 320.691 us; speedup vs baseline: 1.5990x; 1.5990x over previous
//
#include <hip/hip_runtime.h>
#include <stdint.h>

#define N 8192
#define D 256
#define L 4
#define K 1024
#define E 8

#define TM 128            // samples per dist block
#define TN 128            // codes per dist block
#define BK 32             // k-chunk (one MFMA k-step)
#define KSPLIT (K / TN)   // 8
#define MAXTILES (N / TM + E)   // 72
#define TH 4e-4f          // candidate threshold >> 2*bf16x3 error (~2e-5)
#define MAXC 96

typedef unsigned long long u64;
typedef __attribute__((ext_vector_type(8))) short bf16x8;
typedef __attribute__((ext_vector_type(4))) float f32x4;

__device__ __forceinline__ unsigned f2sort(float f) {
    unsigned u = __float_as_uint(f);
    return (u & 0x80000000u) ? ~u : (u | 0x80000000u);
}
__device__ __forceinline__ float sort2f(unsigned s) {
    unsigned u = (s & 0x80000000u) ? (s & 0x7fffffffu) : ~s;
    return __uint_as_float(u);
}
__device__ __forceinline__ u64 umin64(u64 a, u64 b) { return a < b ? a : b; }
__device__ __forceinline__ u64 umax64(u64 a, u64 b) { return a > b ? a : b; }

// manual RNE f32->bf16 (finite inputs)
__device__ __forceinline__ unsigned short f2bf(float f) {
    unsigned u = __float_as_uint(f);
    unsigned r = (u + 0x7fffu + ((u >> 16) & 1u)) >> 16;
    return (unsigned short)r;
}
__device__ __forceinline__ float bf2f(unsigned short h) {
    return __uint_as_float(((unsigned)h) << 16);
}

__device__ __forceinline__ void gload_lds16(const void* g, void* l) {
    __builtin_amdgcn_global_load_lds(
        (const __attribute__((address_space(1))) unsigned int*)(g),
        (__attribute__((address_space(3))) unsigned int*)(l), 16, 0, 0);
}

// exact fp32 distance, summation order IDENTICAL to the original full-scan
__device__ __forceinline__ float exact_dist(const float* __restrict__ crow,
                                            const float* __restrict__ rrow,
                                            float c2v) {
    float dot = 0.f;
    for (int d0 = 0; d0 < D; d0 += 4) {
        float4 c4 = *reinterpret_cast<const float4*>(crow + d0);
        float4 s4 = *reinterpret_cast<const float4*>(rrow + d0);
        dot = fmaf(s4.x, c4.x, dot);
        dot = fmaf(s4.y, c4.y, dot);
        dot = fmaf(s4.z, c4.z, dot);
        dot = fmaf(s4.w, c4.w, dot);
    }
    return c2v - 2.0f * dot;
}

// ------------------------------------------------------------- gate ---------
// NOTE: no atomics here — 8192 same-line atomicAdds cost ~98us (R4 counters).
__global__ void gate_kernel(const float* __restrict__ x,
                            const float* __restrict__ gW,
                            const float* __restrict__ gb,
                            int* __restrict__ eid,
                            float* __restrict__ out_idx,
                            unsigned short* __restrict__ rhi,
                            unsigned short* __restrict__ rlo) {
    int wid = threadIdx.x >> 6, lane = threadIdx.x & 63;
    int n = blockIdx.x * 4 + wid;
    float4 xv = *reinterpret_cast<const float4*>(x + (size_t)n * D + lane * 4);

    ushort4 h4, l4;
    h4.x = f2bf(xv.x); l4.x = f2bf(xv.x - bf2f(h4.x));
    h4.y = f2bf(xv.y); l4.y = f2bf(xv.y - bf2f(h4.y));
    h4.z = f2bf(xv.z); l4.z = f2bf(xv.z - bf2f(h4.z));
    h4.w = f2bf(xv.w); l4.w = f2bf(xv.w - bf2f(h4.w));
    *reinterpret_cast<ushort4*>(rhi + (size_t)n * D + lane * 4) = h4;
    *reinterpret_cast<ushort4*>(rlo + (size_t)n * D + lane * 4) = l4;

    float xa[4] = {xv.x, xv.y, xv.z, xv.w};
    float a[8];
#pragma unroll
    for (int e = 0; e < 8; e++) a[e] = 0.f;
    const float* wr = gW + (size_t)(lane * 4) * E;
#pragma unroll
    for (int i = 0; i < 4; i++) {
        float xs = xa[i];
        float4 w0 = *reinterpret_cast<const float4*>(wr + i * E);
        float4 w1 = *reinterpret_cast<const float4*>(wr + i * E + 4);
        a[0] = fmaf(xs, w0.x, a[0]); a[1] = fmaf(xs, w0.y, a[1]);
        a[2] = fmaf(xs, w0.z, a[2]); a[3] = fmaf(xs, w0.w, a[3]);
        a[4] = fmaf(xs, w1.x, a[4]); a[5] = fmaf(xs, w1.y, a[5]);
        a[6] = fmaf(xs, w1.z, a[6]); a[7] = fmaf(xs, w1.w, a[7]);
    }
#pragma unroll
    for (int off = 32; off > 0; off >>= 1) {
#pragma unroll
        for (int e = 0; e < 8; e++) a[e] += __shfl_xor(a[e], off);
    }
    if (lane == 0) {
        int be = 0;
        float bv = a[0] + gb[0];
        for (int e = 1; e < 8; e++) {
            float v = a[e] + gb[e];
            if (v > bv) { bv = v; be = e; }
        }
        eid[n] = be;
        out_idx[(size_t)n * (L + 1) + L] = (float)be;
    }
}

// ---------------- deterministic counting sort by expert (zero atomics) ------
__global__ __launch_bounds__(256)
void bucket_kernel(const int* __restrict__ eid, int* __restrict__ counts,
                   int* __restrict__ order) {
    __shared__ u64 wtot_lo[4], wtot_hi[4];
    __shared__ int base[E];
    int tid = threadIdx.x, lane = tid & 63, wv = tid >> 6;
    int n0 = tid * 32;
    int eids[32];
    u64 lo = 0, hi = 0;
#pragma unroll
    for (int j = 0; j < 32; j++) {
        int e = eid[n0 + j];
        eids[j] = e;
        if (e < 4) lo += 1ull << (e * 16);
        else       hi += 1ull << ((e - 4) * 16);
    }
    u64 slo = lo, shi = hi;
#pragma unroll
    for (int d = 1; d < 64; d <<= 1) {
        u64 t1 = __shfl_up(slo, d);
        u64 t2 = __shfl_up(shi, d);
        if (lane >= d) { slo += t1; shi += t2; }
    }
    if (lane == 63) { wtot_lo[wv] = slo; wtot_hi[wv] = shi; }
    __syncthreads();
    u64 wofflo = 0, woffhi = 0;
    for (int w = 0; w < wv; w++) { wofflo += wtot_lo[w]; woffhi += wtot_hi[w]; }
    u64 exlo = wofflo + slo - lo;
    u64 exhi = woffhi + shi - hi;
    if (tid == 0) {
        u64 tlo = wtot_lo[0] + wtot_lo[1] + wtot_lo[2] + wtot_lo[3];
        u64 thi = wtot_hi[0] + wtot_hi[1] + wtot_hi[2] + wtot_hi[3];
        int a = 0;
#pragma unroll
        for (int e = 0; e < 4; e++) {
            int c = (int)((tlo >> (e * 16)) & 0xffff);
            counts[e] = c; base[e] = a; a += c;
        }
#pragma unroll
        for (int e = 0; e < 4; e++) {
            int c = (int)((thi >> (e * 16)) & 0xffff);
            counts[4 + e] = c; base[4 + e] = a; a += c;
        }
    }
    __syncthreads();
#pragma unroll
    for (int j = 0; j < 32; j++) {
        int e = eids[j];
        int p;
        if (e < 4) { p = (int)((exlo >> (e * 16)) & 0xffff); exlo += 1ull << (e * 16); }
        else       { p = (int)((exhi >> ((e - 4) * 16)) & 0xffff); exhi += 1ull << ((e - 4) * 16); }
        order[base[e] + p] = n0 + j;
    }
}

// --------------------------------------- codebook prep: c2 + bf16 hi/lo -----
__global__ void cb_prep(const float* __restrict__ cbs, float* __restrict__ c2,
                        unsigned short* __restrict__ cbhi,
                        unsigned short* __restrict__ cblo) {
    int wid = threadIdx.x >> 6, lane = threadIdx.x & 63;
    size_t row = (size_t)blockIdx.x * 4 + wid;
    float4 v = *reinterpret_cast<const float4*>(cbs + row * D + lane * 4);
    ushort4 h4, l4;
    h4.x = f2bf(v.x); l4.x = f2bf(v.x - bf2f(h4.x));
    h4.y = f2bf(v.y); l4.y = f2bf(v.y - bf2f(h4.y));
    h4.z = f2bf(v.z); l4.z = f2bf(v.z - bf2f(h4.z));
    h4.w = f2bf(v.w); l4.w = f2bf(v.w - bf2f(h4.w));
    *reinterpret_cast<ushort4*>(cbhi + row * D + lane * 4) = h4;
    *reinterpret_cast<ushort4*>(cblo + row * D + lane * 4) = l4;
    float s = v.x * v.x + v.y * v.y + v.z * v.z + v.w * v.w;
#pragma unroll
    for (int off = 32; off > 0; off >>= 1) s += __shfl_xor(s, off);
    if (lane == 0) c2[row] = s;
}

// ------------------------------------------------------------ distances -----
__global__ __launch_bounds__(256, 2)
void dist_kernel(const unsigned short* __restrict__ rhi,
                 const unsigned short* __restrict__ rlo,
                 const unsigned short* __restrict__ cbhi,
                 const unsigned short* __restrict__ cblo,
                 const float* __restrict__ c2l,
                 const int* __restrict__ order, const int* __restrict__ counts,
                 uint4* __restrict__ ws2) {
    __shared__ short lA[2][TM * 64];
    __shared__ short lB[2][TN * 64];

    int bx = blockIdx.x;
    int tile = bx >> 3, kc = bx & 7;

    int eoffL[E + 1]; int a = 0;
#pragma unroll
    for (int i = 0; i < E; i++) { eoffL[i] = a; a += counts[i]; }
    eoffL[E] = a;

    int e = -1, lt = 0, cnt = 0, cum = 0;
    for (int i = 0; i < E; i++) {
        int c = counts[i];
        int t = (c + TM - 1) / TM;
        if (tile < cum + t) { e = i; lt = tile - cum; cnt = c; break; }
        cum += t;
    }
    if (e < 0) return;
    int base = eoffL[e] + lt * TM;
    int mcnt = min(TM, cnt - lt * TM);
    int k0 = kc * TN;

    int tid = threadIdx.x;
    int lane = tid & 63, wv = tid >> 6;
    int wr = wv >> 1, wc = wv & 1;

    int srow[4], scol[4], nid[4];
#pragma unroll
    for (int i = 0; i < 4; i++) {
        int s = i * 256 + tid;
        srow[i] = s >> 3;
        scol[i] = (s & 7) ^ (srow[i] & 7);
        nid[i] = 0;
    }
#pragma unroll
    for (int i = 0; i < 4; i++) nid[i] = order[min(base + srow[i], N - 1)];

    const size_t cbbase = ((size_t)e * K + k0) * D;

    f32x4 acc[4][4];
#pragma unroll
    for (int fr = 0; fr < 4; fr++)
#pragma unroll
        for (int fc = 0; fc < 4; fc++)
            acc[fr][fc] = (f32x4){0.f, 0.f, 0.f, 0.f};

    auto STAGE = [&](int buf, int ck) {
        int dc = ck * BK;
#pragma unroll
        for (int i = 0; i < 4; i++) {
            int s = i * 256 + tid, c = scol[i];
            const unsigned short* src = (c < 4)
                ? (rhi + (size_t)nid[i] * D + dc + c * 8)
                : (rlo + (size_t)nid[i] * D + dc + (c - 4) * 8);
            gload_lds16(src, &lA[buf][s * 8]);
        }
#pragma unroll
        for (int i = 0; i < 4; i++) {
            int s = i * 256 + tid, c = scol[i];
            const unsigned short* src = (c < 4)
                ? (cbhi + cbbase + (size_t)srow[i] * D + dc + c * 8)
                : (cblo + cbbase + (size_t)srow[i] * D + dc + (c - 4) * 8);
            gload_lds16(src, &lB[buf][s * 8]);
        }
    };

    int q = lane >> 4, rL = lane & 15;
    STAGE(0, 0);
    for (int ck = 0; ck < D / BK; ck++) {
        __syncthreads();
        if (ck < D / BK - 1) STAGE((ck + 1) & 1, ck + 1);
        int buf = ck & 1;
        bf16x8 ah[4], al[4];
#pragma unroll
        for (int fr = 0; fr < 4; fr++) {
            int row = wr * 64 + fr * 16 + rL;
            ah[fr] = *reinterpret_cast<const bf16x8*>(&lA[buf][row * 64 + ((q) ^ (row & 7)) * 8]);
            al[fr] = *reinterpret_cast<const bf16x8*>(&lA[buf][row * 64 + ((4 + q) ^ (row & 7)) * 8]);
        }
#pragma unroll
        for (int fc = 0; fc < 4; fc++) {
            int row = wc * 64 + fc * 16 + rL;
            bf16x8 bh = *reinterpret_cast<const bf16x8*>(&lB[buf][row * 64 + ((q) ^ (row & 7)) * 8]);
            bf16x8 bl = *reinterpret_cast<const bf16x8*>(&lB[buf][row * 64 + ((4 + q) ^ (row & 7)) * 8]);
#pragma unroll
            for (int fr = 0; fr < 4; fr++) {
                acc[fr][fc] = __builtin_amdgcn_mfma_f32_16x16x32_bf16(ah[fr], bh, acc[fr][fc], 0, 0, 0);
                acc[fr][fc] = __builtin_amdgcn_mfma_f32_16x16x32_bf16(ah[fr], bl, acc[fr][fc], 0, 0, 0);
                acc[fr][fc] = __builtin_amdgcn_mfma_f32_16x16x32_bf16(al[fr], bh, acc[fr][fc], 0, 0, 0);
            }
        }
    }

    int cL = lane & 15;
#pragma unroll
    for (int fr = 0; fr < 4; fr++) {
#pragma unroll
        for (int j = 0; j < 4; j++) {
            int row_local = wr * 64 + fr * 16 + q * 4 + j;
            u64 best = ~0ull; unsigned sec = 0xFFFFFFFFu;
#pragma unroll
            for (int fc = 0; fc < 4; fc++) {
                int col = k0 + wc * 64 + fc * 16 + cL;
                float dist = c2l[e * K + col] - 2.0f * acc[fr][fc][j];
                u64 kk = ((u64)f2sort(dist) << 32) | (unsigned)col;
                u64 mx = umax64(best, kk);
                best = umin64(best, kk);
                sec = min(sec, (unsigned)(mx >> 32));
            }
#pragma unroll
            for (int m = 1; m < 16; m <<= 1) {
                u64 ob = __shfl_xor(best, m, 16);
                unsigned os = __shfl_xor(sec, m, 16);
                u64 mx = umax64(best, ob);
                best = umin64(best, ob);
                sec = min(min(sec, os), (unsigned)(mx >> 32));
            }
            if (cL == 0 && row_local < mcnt) {
                int n = order[base + row_local];
                uint4 v;
                v.x = (unsigned)(best & 0xffffffffu);
                v.y = (unsigned)(best >> 32);
                v.z = sec; v.w = 0;
                ws2[(size_t)n * 16 + kc * 2 + wc] = v;
            }
        }
    }
}

// ---------------- resolve + CANDIDATE-limited exact rescore + update --------
// R7 postmortem: full-1024 rescan pushed ~1MB through ONE CU's miss queue
// (~11 GB/s/CU) => 80-100us straggler blocks. True argmin provably lies among
// chunk-bests within TH of global best (+ full chunks whose SECOND is within
// TH). Rescore only those (typically 2 rows, cap MAXC, full-scan fallback).
__global__ __launch_bounds__(256)
void finalize_kernel(const float* __restrict__ rin, float* __restrict__ resid,
                     const float* __restrict__ cbl, const uint4* __restrict__ ws2,
                     const int* __restrict__ eid, const float* __restrict__ x,
                     float* __restrict__ out, float* __restrict__ lossb,
                     const float* __restrict__ c2l,
                     unsigned short* __restrict__ rhi,
                     unsigned short* __restrict__ rlo, int l) {
    __shared__ int s_idx[4];
    __shared__ int s_eid[4];
    __shared__ float s_bd[4];
    __shared__ int s_flag[4];
    __shared__ int s_fcount;
    __shared__ int s_cand[MAXC];
    __shared__ u64 s_res[MAXC];
    __shared__ int s_nc;
    __shared__ unsigned s_scanmask;
    __shared__ int s_base;
    __shared__ u64 s_rb[4];
    __shared__ float s_ls[4];

    int tid = threadIdx.x, lane = tid & 63, wv = tid >> 6;
    int n0 = blockIdx.x * 4;
    if (tid == 0) s_fcount = 0;
    __syncthreads();

    // ---- phase A: wave 0 resolves all 4 samples (16 lanes each)
    if (wv == 0) {
        int sloc = lane >> 4;
        int n = n0 + sloc;
        int l16 = lane & 15;
        uint4 ev = ws2[(size_t)n * 16 + l16];
        u64 best = ((u64)ev.y << 32) | ev.x;
        float mybest = sort2f(ev.y);
        float mysec = sort2f(ev.z);
#pragma unroll
        for (int m = 1; m < 16; m <<= 1)
            best = umin64(best, __shfl_xor(best, m, 16));
        float bd = sort2f((unsigned)(best >> 32));
        // rescore trigger: any OTHER candidate within TH of global best
        u64 b1 = __ballot(mybest <= bd + TH);
        u64 b2 = __ballot(mysec <= bd + TH);
        if (l16 == 0) {
            s_idx[sloc] = (int)(best & 0xffffffffu);
            s_eid[sloc] = eid[n];
            s_bd[sloc] = bd;
            unsigned m1 = (unsigned)(b1 >> (sloc * 16)) & 0xFFFFu;
            unsigned m2 = (unsigned)(b2 >> (sloc * 16)) & 0xFFFFu;
            if (__popc(m1) > 1 || m2 != 0) {
                int p = atomicAdd(&s_fcount, 1);
                s_flag[p] = sloc;
            }
        }
    }
    __syncthreads();
    int fc = s_fcount;

    // ---- phase B: candidate-limited exact rescore (rare)
    for (int f = 0; f < fc; f++) {
        int sloc = s_flag[f];
        int n = n0 + sloc, e = s_eid[sloc];
        float bd = s_bd[sloc];
        const float* rrow = rin + (size_t)n * D;
        if (tid == 0) { s_nc = 0; s_scanmask = 0; }
        __syncthreads();
        if (tid < 16) {
            uint4 ev = ws2[(size_t)n * 16 + tid];
            if (sort2f(ev.y) <= bd + TH) {
                int p = atomicAdd(&s_nc, 1);
                if (p < MAXC) s_cand[p] = (int)ev.x;
            }
            if (sort2f(ev.z) <= bd + TH)
                atomicOr(&s_scanmask, 1u << tid);
        }
        __syncthreads();
        unsigned sm = s_scanmask;      // block-uniform
        while (sm) {
            int c = __ffs(sm) - 1; sm &= sm - 1;
            if (tid == 0) s_base = atomicAdd(&s_nc, 64);
            __syncthreads();
            if (tid < 64 && s_base + tid < MAXC) {
                int half = tid >> 5;           // chunk c covers cols (c*64..c*64+63)
                s_cand[s_base + tid] = (c >> 1) * TN + (c & 1) * 64 + (half * 32) + (tid & 31);
            }
            __syncthreads();
        }
        __syncthreads();
        int nc = s_nc;
        if (nc > MAXC) {
            // fallback: old full scan (essentially never)
            u64 rb = ~0ull;
            for (int c = 0; c < 4; c++) {
                int k = c * 256 + tid;
                float dist = exact_dist(cbl + ((size_t)e * K + k) * D, rrow,
                                        c2l[e * K + k]);
                rb = umin64(rb, ((u64)f2sort(dist) << 32) | (unsigned)k);
            }
#pragma unroll
            for (int m = 1; m < 64; m <<= 1) rb = umin64(rb, __shfl_xor(rb, m));
            if (lane == 0) s_rb[wv] = rb;
            __syncthreads();
            if (tid == 0) {
                rb = umin64(umin64(s_rb[0], s_rb[1]), umin64(s_rb[2], s_rb[3]));
                s_idx[sloc] = (int)(rb & 0xffffffffu);
            }
            __syncthreads();
        } else {
            if (tid < nc) {
                int k = s_cand[tid];
                float dist = exact_dist(cbl + ((size_t)e * K + k) * D, rrow,
                                        c2l[e * K + k]);
                s_res[tid] = ((u64)f2sort(dist) << 32) | (unsigned)k;
            }
            __syncthreads();
            if (tid == 0) {
                u64 rb = ~0ull;
                for (int i = 0; i < nc; i++) rb = umin64(rb, s_res[i]);
                s_idx[sloc] = (int)(rb & 0xffffffffu);
            }
            __syncthreads();
        }
    }

    // ---- phase C: streaming update; wave wv owns sample wv (64 f4-chunks)
    int sloc = wv, f4p = lane;
    int n = n0 + sloc;
    int e = s_eid[sloc], idx = s_idx[sloc];
    const float* qrow = cbl + ((size_t)e * K + idx) * D;
    float4 q4 = *reinterpret_cast<const float4*>(qrow + f4p * 4);
    float4 r4 = *reinterpret_cast<const float4*>(rin + (size_t)n * D + f4p * 4);
    float dx = q4.x - r4.x, dy = q4.y - r4.y, dz = q4.z - r4.z, dw = q4.w - r4.w;
    float lsum = dx * dx + dy * dy + dz * dz + dw * dw;
    float4 nr = make_float4(r4.x - q4.x, r4.y - q4.y, r4.z - q4.z, r4.w - q4.w);
    if (l < L - 1) {
        *reinterpret_cast<float4*>(resid + (size_t)n * D + f4p * 4) = nr;
        ushort4 h4, l4w;
        h4.x = f2bf(nr.x); l4w.x = f2bf(nr.x - bf2f(h4.x));
        h4.y = f2bf(nr.y); l4w.y = f2bf(nr.y - bf2f(h4.y));
        h4.z = f2bf(nr.z); l4w.z = f2bf(nr.z - bf2f(h4.z));
        h4.w = f2bf(nr.w); l4w.w = f2bf(nr.w - bf2f(h4.w));
        *reinterpret_cast<ushort4*>(rhi + (size_t)n * D + f4p * 4) = h4;
        *reinterpret_cast<ushort4*>(rlo + (size_t)n * D + f4p * 4) = l4w;
    } else {
        float4 x4 = *reinterpret_cast<const float4*>(x + (size_t)n * D + f4p * 4);
        float4 xq = make_float4(x4.x - nr.x, x4.y - nr.y, x4.z - nr.z, x4.w - nr.w);
        *reinterpret_cast<float4*>(out + (size_t)n * D + f4p * 4) = xq;
    }
    if (f4p == 0)
        out[(size_t)N * D + 1 + (size_t)n * (L + 1) + l] = (float)idx;
#pragma unroll
    for (int m = 1; m < 64; m <<= 1) lsum += __shfl_xor(lsum, m);
    if (lane == 0) s_ls[wv] = lsum;
    __syncthreads();
    if (tid == 0)   // bucket padded to one cache line each (no same-line contention)
        atomicAdd(&lossb[(blockIdx.x & 31) * 32], s_ls[0] + s_ls[1] + s_ls[2] + s_ls[3]);
}

__global__ void loss_fin_kernel(const float* __restrict__ lossb, float* __restrict__ out) {
    float s = 0.f;
    for (int i = 0; i < 32; i++) s += lossb[i * 32];
    out[(size_t)N * D] = 2.0f * s / ((float)N * (float)D * (float)L);
}

// ----------------------------------------------------------------------------
extern "C" void kernel_launch(void* const* d_in, const int* in_sizes, int n_in,
                              void* d_out, int out_size, void* d_ws, size_t ws_size,
                              hipStream_t stream) {
    const float* x   = (const float*)d_in[0];
    // d_in[1] = labels (unused)
    const float* cbs = (const float*)d_in[2];
    const float* gW  = (const float*)d_in[3];
    const float* gb  = (const float*)d_in[4];
    float* out = (float*)d_out;

    char* ws = (char*)d_ws;
    float*          resid = (float*)(ws);                       //  8,388,608
    unsigned short* rhi   = (unsigned short*)(ws + 8388608);    //  4,194,304
    unsigned short* rlo   = (unsigned short*)(ws + 12582912);   //  4,194,304
    unsigned short* cbhi  = (unsigned short*)(ws + 16777216);   // 16,777,216
    unsigned short* cblo  = (unsigned short*)(ws + 33554432);   // 16,777,216
    float*          c2    = (float*)(ws + 50331648);            //    131,072
    int*            eid   = (int*)(ws + 50462720);              //     32,768
    int*            order = (int*)(ws + 50495488);              //     33,280
    uint4*          ws2   = (uint4*)(ws + 50528768);            //  2,097,152
    char*           smallp = ws + 52625920;
    int*   counts  = (int*)(smallp);          // 32 B
    float* lossb   = (float*)(smallp + 128);  // 32 buckets x 128 B = 4 KB

    hipMemsetAsync(smallp, 0, 4352, stream);

    gate_kernel<<<N / 4, 256, 0, stream>>>(x, gW, gb, eid,
                                           out + (size_t)N * D + 1, rhi, rlo);
    bucket_kernel<<<1, 256, 0, stream>>>(eid, counts, order);
    cb_prep<<<(L * E * K) / 4, 256, 0, stream>>>(cbs, c2, cbhi, cblo);

    for (int l = 0; l < L; l++) {
        const float* rin = (l == 0) ? x : resid;
        size_t cboff = (size_t)l * E * K * D;
        const float* c2l = c2 + (size_t)l * E * K;
        dist_kernel<<<MAXTILES * KSPLIT, 256, 0, stream>>>(
            rhi, rlo, cbhi + cboff, cblo + cboff, c2l, order, counts, ws2);
        finalize_kernel<<<N / 4, 256, 0, stream>>>(
            rin, resid, cbs + cboff, ws2, eid, x, out, lossb, c2l, rhi, rlo, l);
    }
    loss_fin_kernel<<<1, 1, 0, stream>>>(lossb, out);
}